// Round 17
// baseline (48.446 us; speedup 1.0000x reference)
//
#include <hip/hip_runtime.h>
#include <hip/hip_fp16.h>

typedef float  f32x4  __attribute__((ext_vector_type(4)));
typedef float  v2f    __attribute__((ext_vector_type(2)));
typedef short  bf16x8 __attribute__((ext_vector_type(8)));

#define KS 7
#define NG 16
#define PAD 3
#define NB 4
#define NC 64
#define NH 128
#define NW 128
#define HW (NH*NW)
#define NR 16
#define CG 4
#define KK 49
#define L2E 1.44269504088896f
#define PADB -100000.0f
#define TS 16
#define HT 22

__device__ __forceinline__ unsigned short bf16rn(float f) {
    unsigned u = __float_as_uint(f);
    u += 0x7FFFu + ((u >> 16) & 1u);
    return (unsigned short)(u >> 16);
}
__device__ __forceinline__ float bf16tof(unsigned short h) {
    return __uint_as_float(((unsigned)h) << 16);
}

// ---- Kernel A: redpk[b*HW+px][32] = [bf16_hi(relu(conv)*log2e) x16 | bf16_lo x16]
// 8-way rq split: 2 r's per thread, 2048 blocks -> 32 waves/CU supplied.
// Numerically identical per-r FMA chain to the 4-way version.
__global__ __launch_bounds__(256)
void red_kernel(const float* __restrict__ x,
                const float* __restrict__ w_reduce,
                const float* __restrict__ b_reduce,
                unsigned short* __restrict__ redpk) {
    __shared__ float wT[NC][2];
    const int t  = threadIdx.x;
    const int rq = blockIdx.y;                 // 0..7: which 2 r's
    if (t < 128) wT[t & 63][t >> 6] = w_reduce[(rq*2 + (t >> 6))*NC + (t & 63)];
    __syncthreads();

    const int pth = blockIdx.x*256 + t;        // 0..65535 = b*16384+pix
    const int b   = pth >> 14;
    const int pix = pth & 16383;

    float a0 = b_reduce[rq*2 + 0];
    float a1 = b_reduce[rq*2 + 1];

    const float* xp = x + (size_t)b*(NC*HW) + pix;
    #pragma unroll 16
    for (int c = 0; c < NC; ++c) {
        float xv = xp[(size_t)c*HW];           // coalesced; L2-hot re-read
        float2 ww = *(const float2*)&wT[c][0]; // broadcast
        a0 = fmaf(ww.x, xv, a0);
        a1 = fmaf(ww.y, xv, a1);
    }

    float s0 = fmaxf(a0, 0.f) * L2E;
    float s1 = fmaxf(a1, 0.f) * L2E;
    unsigned short h0 = bf16rn(s0), h1 = bf16rn(s1);
    unsigned short l0 = bf16rn(s0 - bf16tof(h0));
    unsigned short l1 = bf16rn(s1 - bf16tof(h1));
    unsigned short* rp = redpk + ((size_t)pth << 5);
    *(ushort2*)(rp + rq*2)      = make_ushort2(h0, h1);
    *(ushort2*)(rp + 16 + rq*2) = make_ushort2(l0, l1);
}

// ---- Kernel B: EXACT R15 kernel (proven 45.1 us / absmax 1.95e-3). ----------
__global__ __launch_bounds__(256, 4)
void invol_kernel(const float* __restrict__ x,
                  const float* __restrict__ w_span,
                  const float* __restrict__ b_span,
                  const unsigned short* __restrict__ redpk,
                  float* __restrict__ out) {
    __shared__ float4 xs[2][HT][HT];           // 15488 B

    const int t    = threadIdx.x;
    const int lane = t & 63;
    const int wv   = __builtin_amdgcn_readfirstlane(t >> 6);
    const int gi   = wv >> 1;
    const int half = wv & 1;
    const int p    = lane & 15;
    const int q    = lane >> 4;
    const int h0   = (blockIdx.x >> 3) * TS;
    const int w0   = (blockIdx.x & 7) * TS;
    const int g    = blockIdx.y * 2 + gi;
    const int b    = blockIdx.z;

    // ---- stage both groups' 22x22 f32 halos cooperatively ----
    #pragma unroll
    for (int it = 0; it < 4; ++it) {
        int idx = t + it * 256;
        if (idx < 2 * HT * HT) {
            int g2  = idx / (HT * HT);
            int pos = idx - g2 * (HT * HT);
            int hh = pos / HT, ww = pos - hh * HT;
            int gh = h0 + hh - PAD, gw = w0 + ww - PAD;
            float4 v = make_float4(0.f, 0.f, 0.f, 0.f);
            if ((unsigned)gh < NH && (unsigned)gw < NW) {
                const float* pp = x + (size_t)(b*NC + (blockIdx.y*2 + g2)*CG)*HW
                                    + gh*NW + gw;
                v.x = pp[0]; v.y = pp[HW]; v.z = pp[2*HW]; v.w = pp[3*HW];
            }
            xs[g2][hh][ww] = v;
        }
    }
    __syncthreads();

    // ---- A-fragments ----
    const float* wg = w_span + (size_t)g*(KK*NR);
    bf16x8 A1[4];
    #pragma unroll
    for (int tt = 0; tt < 4; ++tt) {
        int tap = tt*16 + p; if (tap > 48) tap = 48;
        const float4* wr = (const float4*)(wg + tap*NR + (q & 1)*8);
        float4 u0 = wr[0], u1 = wr[1];
        float w8[8] = {u0.x,u0.y,u0.z,u0.w,u1.x,u1.y,u1.z,u1.w};
        bf16x8 a;
        #pragma unroll
        for (int i = 0; i < 8; ++i) {
            unsigned short h = bf16rn(w8[i]);
            unsigned short l = bf16rn(w8[i] - bf16tof(h));
            a[i] = (short)(q < 2 ? h : l);
        }
        A1[tt] = a;
    }

    // ---- bias ----
    const float* bg = b_span + g*KK;
    f32x4 bias[4];
    #pragma unroll
    for (int tt = 0; tt < 3; ++tt) {
        float4 bb = *(const float4*)(bg + tt*16 + q*4);
        bias[tt][0] = bb.x*L2E; bias[tt][1] = bb.y*L2E;
        bias[tt][2] = bb.z*L2E; bias[tt][3] = bb.w*L2E;
    }
    bias[3][0] = (q == 0) ? bg[48]*L2E : PADB;
    bias[3][1] = PADB; bias[3][2] = PADB; bias[3][3] = PADB;

    // ---- gather pointers (f32) ----
    const float4* gp[13];
    #pragma unroll
    for (int tt = 0; tt < 3; ++tt) {
        #pragma unroll
        for (int r = 0; r < 4; ++r) {
            int tap = tt*16 + q*4 + r;
            int i = tap / 7, j = tap - i*7;
            gp[tt*4+r] = &xs[gi][i + half*8][p + j];
        }
    }
    gp[12] = &xs[gi][6 + half*8][p + 6];

    bf16x8 zz;
    #pragma unroll
    for (int i = 0; i < 8; ++i) zz[i] = 0;

    const unsigned short* rb =
        redpk + (((size_t)b*HW + (size_t)(h0 + half*8)*NW + w0 + p) << 5)
              + ((q & 1) << 3);
    bf16x8 B1 = *(const bf16x8*)rb;
    bf16x8 B2 = *(const bf16x8*)(rb + 16);
    B2 = (q < 2) ? B2 : zz;

    const int hb = h0 + half*8;

    #pragma unroll
    for (int ph = 0; ph < 8; ++ph) {
        bf16x8 B1n = B1, B2n = B2;
        if (ph < 7) {
            const unsigned short* rn = rb + (size_t)(ph+1)*(NW*32);
            B1n = *(const bf16x8*)rn;
            bf16x8 l2 = *(const bf16x8*)(rn + 16);
            B2n = (q < 2) ? l2 : zz;
        }

        f32x4 ac[4];
        #pragma unroll
        for (int tt = 0; tt < 4; ++tt) {
            f32x4 c0 = __builtin_amdgcn_mfma_f32_16x16x32_bf16(A1[tt], B1, bias[tt], 0,0,0);
            ac[tt]   = __builtin_amdgcn_mfma_f32_16x16x32_bf16(A1[tt], B2, c0,      0,0,0);
        }

        float e[13];
        #pragma unroll
        for (int tt = 0; tt < 3; ++tt) {
            #pragma unroll
            for (int r = 0; r < 4; ++r)
                e[tt*4+r] = __builtin_amdgcn_exp2f(ac[tt][r]);
        }
        e[12] = __builtin_amdgcn_exp2f(ac[3][0]);

        float s0 = (e[0] + e[1]) + (e[2] + e[3]);
        float s1 = (e[4] + e[5]) + (e[6] + e[7]);
        float s2 = (e[8] + e[9]) + (e[10] + e[11]);
        float sum = (s0 + s1) + (s2 + e[12]);
        sum += __shfl_xor(sum, 16);
        sum += __shfl_xor(sum, 32);

        v2f a01 = {0.f, 0.f}, a23 = {0.f, 0.f};
        #pragma unroll
        for (int k = 0; k < 13; ++k) {
            float4 v = gp[k][ph*HT];
            v2f ee = {e[k], e[k]};
            a01 += ee * (v2f){v.x, v.y};       // v_pk_fma_f32
            a23 += ee * (v2f){v.z, v.w};
        }
        float g0 = a01[0], g1 = a01[1], g2 = a23[0], g3 = a23[1];
        g0 += __shfl_xor(g0, 16); g0 += __shfl_xor(g0, 32);
        g1 += __shfl_xor(g1, 16); g1 += __shfl_xor(g1, 32);
        g2 += __shfl_xor(g2, 16); g2 += __shfl_xor(g2, 32);
        g3 += __shfl_xor(g3, 16); g3 += __shfl_xor(g3, 32);

        if (q == 0) {
            float inv = 1.0f / sum;
            const int h = hb + ph, w = w0 + p;
            size_t ob = ((size_t)(b*NC + g*CG)*NH + h)*NW + w;
            out[ob]        = g0 * inv;
            out[ob + HW]   = g1 * inv;
            out[ob + 2*HW] = g2 * inv;
            out[ob + 3*HW] = g3 * inv;
        }
        B1 = B1n; B2 = B2n;
    }
}

extern "C" void kernel_launch(void* const* d_in, const int* in_sizes, int n_in,
                              void* d_out, int out_size, void* d_ws, size_t ws_size,
                              hipStream_t stream) {
    const float* x        = (const float*)d_in[0];
    const float* w_reduce = (const float*)d_in[1];
    const float* b_reduce = (const float*)d_in[2];
    const float* w_span   = (const float*)d_in[3];
    const float* b_span   = (const float*)d_in[4];
    float* out = (float*)d_out;
    unsigned short* redpk = (unsigned short*)d_ws;   // 4 MB

    red_kernel<<<dim3(NB*HW/256, 8), 256, 0, stream>>>(x, w_reduce, b_reduce, redpk);

    dim3 gridB(64, NG/2, NB);                        // 2048 blocks x 4 waves
    invol_kernel<<<gridB, 256, 0, stream>>>(x, w_span, b_span, redpk, out);
}

// Round 18
// 45.230 us; speedup vs baseline: 1.0711x; 1.0711x over previous
//
#include <hip/hip_runtime.h>
#include <hip/hip_fp16.h>

typedef float  f32x4  __attribute__((ext_vector_type(4)));
typedef float  v2f    __attribute__((ext_vector_type(2)));
typedef short  bf16x8 __attribute__((ext_vector_type(8)));

#define KS 7
#define NG 16
#define PAD 3
#define NB 4
#define NC 64
#define NH 128
#define NW 128
#define HW (NH*NW)
#define NR 16
#define CG 4
#define KK 49
#define L2E 1.44269504088896f
#define PADB -100000.0f
#define TS 16
#define HT 22

__device__ __forceinline__ unsigned short bf16rn(float f) {
    unsigned u = __float_as_uint(f);
    u += 0x7FFFu + ((u >> 16) & 1u);
    return (unsigned short)(u >> 16);
}
__device__ __forceinline__ float bf16tof(unsigned short h) {
    return __uint_as_float(((unsigned)h) << 16);
}

// ---- Kernel A: exact R14/R15 4-way version (proven ~6 us) -------------------
__global__ __launch_bounds__(256)
void red_kernel(const float* __restrict__ x,
                const float* __restrict__ w_reduce,
                const float* __restrict__ b_reduce,
                unsigned short* __restrict__ redpk) {
    __shared__ float wT[NC][4];
    const int t  = threadIdx.x;
    const int rq = blockIdx.y;                 // 0..3: which 4 r's
    { int e = t >> 6, c = t & 63; wT[c][e] = w_reduce[(rq*4+e)*NC + c]; }
    __syncthreads();

    const int pth = blockIdx.x*256 + t;        // 0..65535 = b*16384+pix
    const int b   = pth >> 14;
    const int pix = pth & 16383;

    float aa[4];
    #pragma unroll
    for (int i = 0; i < 4; ++i) aa[i] = b_reduce[rq*4+i];

    const float* xp = x + (size_t)b*(NC*HW) + pix;
    #pragma unroll 16
    for (int c = 0; c < NC; ++c) {
        float xv = xp[(size_t)c*HW];
        float4 ww = *(const float4*)&wT[c][0];
        aa[0] = fmaf(ww.x, xv, aa[0]);
        aa[1] = fmaf(ww.y, xv, aa[1]);
        aa[2] = fmaf(ww.z, xv, aa[2]);
        aa[3] = fmaf(ww.w, xv, aa[3]);
    }

    unsigned short hv[4], lv[4];
    #pragma unroll
    for (int i = 0; i < 4; ++i) {
        float sv = fmaxf(aa[i], 0.f) * L2E;
        unsigned short h = bf16rn(sv);
        hv[i] = h;
        lv[i] = bf16rn(sv - bf16tof(h));
    }
    unsigned short* rp = redpk + ((size_t)pth << 5);
    *(ushort4*)(rp + rq*4)      = make_ushort4(hv[0],hv[1],hv[2],hv[3]);
    *(ushort4*)(rp + 16 + rq*4) = make_ushort4(lv[0],lv[1],lv[2],lv[3]);
}

// ---- Kernel B: R15 structure + gather reads hoisted above MFMA/exp2 ---------
// The 13 ds_read_b128 depend only on ph; issuing them FIRST lets them fly
// on lgkmcnt during the MFMA+exp2 phase, cutting an LDS round-trip from the
// per-row critical path. Pure reordering; numerics identical to R15.
__global__ __launch_bounds__(256, 4)
void invol_kernel(const float* __restrict__ x,
                  const float* __restrict__ w_span,
                  const float* __restrict__ b_span,
                  const unsigned short* __restrict__ redpk,
                  float* __restrict__ out) {
    __shared__ float4 xs[2][HT][HT];           // 15488 B

    const int t    = threadIdx.x;
    const int lane = t & 63;
    const int wv   = __builtin_amdgcn_readfirstlane(t >> 6);
    const int gi   = wv >> 1;
    const int half = wv & 1;
    const int p    = lane & 15;
    const int q    = lane >> 4;
    const int h0   = (blockIdx.x >> 3) * TS;
    const int w0   = (blockIdx.x & 7) * TS;
    const int g    = blockIdx.y * 2 + gi;
    const int b    = blockIdx.z;

    // ---- stage both groups' 22x22 f32 halos cooperatively ----
    #pragma unroll
    for (int it = 0; it < 4; ++it) {
        int idx = t + it * 256;
        if (idx < 2 * HT * HT) {
            int g2  = idx / (HT * HT);
            int pos = idx - g2 * (HT * HT);
            int hh = pos / HT, ww = pos - hh * HT;
            int gh = h0 + hh - PAD, gw = w0 + ww - PAD;
            float4 v = make_float4(0.f, 0.f, 0.f, 0.f);
            if ((unsigned)gh < NH && (unsigned)gw < NW) {
                const float* pp = x + (size_t)(b*NC + (blockIdx.y*2 + g2)*CG)*HW
                                    + gh*NW + gw;
                v.x = pp[0]; v.y = pp[HW]; v.z = pp[2*HW]; v.w = pp[3*HW];
            }
            xs[g2][hh][ww] = v;
        }
    }
    __syncthreads();

    // ---- A-fragments ----
    const float* wg = w_span + (size_t)g*(KK*NR);
    bf16x8 A1[4];
    #pragma unroll
    for (int tt = 0; tt < 4; ++tt) {
        int tap = tt*16 + p; if (tap > 48) tap = 48;
        const float4* wr = (const float4*)(wg + tap*NR + (q & 1)*8);
        float4 u0 = wr[0], u1 = wr[1];
        float w8[8] = {u0.x,u0.y,u0.z,u0.w,u1.x,u1.y,u1.z,u1.w};
        bf16x8 a;
        #pragma unroll
        for (int i = 0; i < 8; ++i) {
            unsigned short h = bf16rn(w8[i]);
            unsigned short l = bf16rn(w8[i] - bf16tof(h));
            a[i] = (short)(q < 2 ? h : l);
        }
        A1[tt] = a;
    }

    // ---- bias ----
    const float* bg = b_span + g*KK;
    f32x4 bias[4];
    #pragma unroll
    for (int tt = 0; tt < 3; ++tt) {
        float4 bb = *(const float4*)(bg + tt*16 + q*4);
        bias[tt][0] = bb.x*L2E; bias[tt][1] = bb.y*L2E;
        bias[tt][2] = bb.z*L2E; bias[tt][3] = bb.w*L2E;
    }
    bias[3][0] = (q == 0) ? bg[48]*L2E : PADB;
    bias[3][1] = PADB; bias[3][2] = PADB; bias[3][3] = PADB;

    // ---- gather pointers (f32) ----
    const float4* gp[13];
    #pragma unroll
    for (int tt = 0; tt < 3; ++tt) {
        #pragma unroll
        for (int r = 0; r < 4; ++r) {
            int tap = tt*16 + q*4 + r;
            int i = tap / 7, j = tap - i*7;
            gp[tt*4+r] = &xs[gi][i + half*8][p + j];
        }
    }
    gp[12] = &xs[gi][6 + half*8][p + 6];

    bf16x8 zz;
    #pragma unroll
    for (int i = 0; i < 8; ++i) zz[i] = 0;

    const unsigned short* rb =
        redpk + (((size_t)b*HW + (size_t)(h0 + half*8)*NW + w0 + p) << 5)
              + ((q & 1) << 3);
    bf16x8 B1 = *(const bf16x8*)rb;
    bf16x8 B2 = *(const bf16x8*)(rb + 16);
    B2 = (q < 2) ? B2 : zz;

    const int hb = h0 + half*8;

    #pragma unroll
    for (int ph = 0; ph < 8; ++ph) {
        // ---- HOISTED: issue all 13 gather reads first (independent of MFMA)
        float4 vv[13];
        #pragma unroll
        for (int k = 0; k < 13; ++k)
            vv[k] = gp[k][ph*HT];              // ds_read_b128, imm offsets

        bf16x8 B1n = B1, B2n = B2;
        if (ph < 7) {
            const unsigned short* rn = rb + (size_t)(ph+1)*(NW*32);
            B1n = *(const bf16x8*)rn;
            bf16x8 l2 = *(const bf16x8*)(rn + 16);
            B2n = (q < 2) ? l2 : zz;
        }

        f32x4 ac[4];
        #pragma unroll
        for (int tt = 0; tt < 4; ++tt) {
            f32x4 c0 = __builtin_amdgcn_mfma_f32_16x16x32_bf16(A1[tt], B1, bias[tt], 0,0,0);
            ac[tt]   = __builtin_amdgcn_mfma_f32_16x16x32_bf16(A1[tt], B2, c0,      0,0,0);
        }

        float e[13];
        #pragma unroll
        for (int tt = 0; tt < 3; ++tt) {
            #pragma unroll
            for (int r = 0; r < 4; ++r)
                e[tt*4+r] = __builtin_amdgcn_exp2f(ac[tt][r]);
        }
        e[12] = __builtin_amdgcn_exp2f(ac[3][0]);

        float s0 = (e[0] + e[1]) + (e[2] + e[3]);
        float s1 = (e[4] + e[5]) + (e[6] + e[7]);
        float s2 = (e[8] + e[9]) + (e[10] + e[11]);
        float sum = (s0 + s1) + (s2 + e[12]);
        sum += __shfl_xor(sum, 16);
        sum += __shfl_xor(sum, 32);

        v2f a01 = {0.f, 0.f}, a23 = {0.f, 0.f};
        #pragma unroll
        for (int k = 0; k < 13; ++k) {
            float4 v = vv[k];
            v2f ee = {e[k], e[k]};
            a01 += ee * (v2f){v.x, v.y};       // v_pk_fma_f32
            a23 += ee * (v2f){v.z, v.w};
        }
        float g0 = a01[0], g1 = a01[1], g2 = a23[0], g3 = a23[1];
        g0 += __shfl_xor(g0, 16); g0 += __shfl_xor(g0, 32);
        g1 += __shfl_xor(g1, 16); g1 += __shfl_xor(g1, 32);
        g2 += __shfl_xor(g2, 16); g2 += __shfl_xor(g2, 32);
        g3 += __shfl_xor(g3, 16); g3 += __shfl_xor(g3, 32);

        if (q == 0) {
            float inv = 1.0f / sum;
            const int h = hb + ph, w = w0 + p;
            size_t ob = ((size_t)(b*NC + g*CG)*NH + h)*NW + w;
            out[ob]        = g0 * inv;
            out[ob + HW]   = g1 * inv;
            out[ob + 2*HW] = g2 * inv;
            out[ob + 3*HW] = g3 * inv;
        }
        B1 = B1n; B2 = B2n;
    }
}

extern "C" void kernel_launch(void* const* d_in, const int* in_sizes, int n_in,
                              void* d_out, int out_size, void* d_ws, size_t ws_size,
                              hipStream_t stream) {
    const float* x        = (const float*)d_in[0];
    const float* w_reduce = (const float*)d_in[1];
    const float* b_reduce = (const float*)d_in[2];
    const float* w_span   = (const float*)d_in[3];
    const float* b_span   = (const float*)d_in[4];
    float* out = (float*)d_out;
    unsigned short* redpk = (unsigned short*)d_ws;   // 4 MB

    red_kernel<<<dim3(NB*HW/256, 4), 256, 0, stream>>>(x, w_reduce, b_reduce, redpk);

    dim3 gridB(64, NG/2, NB);                        // 2048 blocks x 4 waves
    invol_kernel<<<gridB, 256, 0, stream>>>(x, w_span, b_span, redpk, out);
}

// Round 19
// 45.045 us; speedup vs baseline: 1.0755x; 1.0041x over previous
//
#include <hip/hip_runtime.h>
#include <hip/hip_fp16.h>

typedef float  f32x4  __attribute__((ext_vector_type(4)));
typedef float  v2f    __attribute__((ext_vector_type(2)));
typedef short  bf16x8 __attribute__((ext_vector_type(8)));

#define KS 7
#define NG 16
#define PAD 3
#define NB 4
#define NC 64
#define NH 128
#define NW 128
#define HW (NH*NW)
#define NR 16
#define CG 4
#define KK 49
#define L2E 1.44269504088896f
#define PADB -100000.0f
#define TS 16
#define HT 22

__device__ __forceinline__ unsigned short bf16rn(float f) {
    unsigned u = __float_as_uint(f);
    u += 0x7FFFu + ((u >> 16) & 1u);
    return (unsigned short)(u >> 16);
}
__device__ __forceinline__ float bf16tof(unsigned short h) {
    return __uint_as_float(((unsigned)h) << 16);
}

// ---- Kernel A: exact R15/R18 4-way version (proven) -------------------------
__global__ __launch_bounds__(256)
void red_kernel(const float* __restrict__ x,
                const float* __restrict__ w_reduce,
                const float* __restrict__ b_reduce,
                unsigned short* __restrict__ redpk) {
    __shared__ float wT[NC][4];
    const int t  = threadIdx.x;
    const int rq = blockIdx.y;                 // 0..3: which 4 r's
    { int e = t >> 6, c = t & 63; wT[c][e] = w_reduce[(rq*4+e)*NC + c]; }
    __syncthreads();

    const int pth = blockIdx.x*256 + t;        // 0..65535 = b*16384+pix
    const int b   = pth >> 14;
    const int pix = pth & 16383;

    float aa[4];
    #pragma unroll
    for (int i = 0; i < 4; ++i) aa[i] = b_reduce[rq*4+i];

    const float* xp = x + (size_t)b*(NC*HW) + pix;
    #pragma unroll 16
    for (int c = 0; c < NC; ++c) {
        float xv = xp[(size_t)c*HW];
        float4 ww = *(const float4*)&wT[c][0];
        aa[0] = fmaf(ww.x, xv, aa[0]);
        aa[1] = fmaf(ww.y, xv, aa[1]);
        aa[2] = fmaf(ww.z, xv, aa[2]);
        aa[3] = fmaf(ww.w, xv, aa[3]);
    }

    unsigned short hv[4], lv[4];
    #pragma unroll
    for (int i = 0; i < 4; ++i) {
        float sv = fmaxf(aa[i], 0.f) * L2E;
        unsigned short h = bf16rn(sv);
        hv[i] = h;
        lv[i] = bf16rn(sv - bf16tof(h));
    }
    unsigned short* rp = redpk + ((size_t)pth << 5);
    *(ushort4*)(rp + rq*4)      = make_ushort4(hv[0],hv[1],hv[2],hv[3]);
    *(ushort4*)(rp + 16 + rq*4) = make_ushort4(lv[0],lv[1],lv[2],lv[3]);
}

// ---- Kernel B: R18 minus the B2 zero-mask. --------------------------------
// Keeping r_lo live for q>=2 lanes adds the w_lo*r_lo cross-term, making the
// product (w_hi+w_lo)*(r_hi+r_lo) — exact w.r.t. the bf16 splits (MORE
// accurate than masking) — and removes the per-row cndmask/zz path.
__global__ __launch_bounds__(256, 4)
void invol_kernel(const float* __restrict__ x,
                  const float* __restrict__ w_span,
                  const float* __restrict__ b_span,
                  const unsigned short* __restrict__ redpk,
                  float* __restrict__ out) {
    __shared__ float4 xs[2][HT][HT];           // 15488 B

    const int t    = threadIdx.x;
    const int lane = t & 63;
    const int wv   = __builtin_amdgcn_readfirstlane(t >> 6);
    const int gi   = wv >> 1;
    const int half = wv & 1;
    const int p    = lane & 15;
    const int q    = lane >> 4;
    const int h0   = (blockIdx.x >> 3) * TS;
    const int w0   = (blockIdx.x & 7) * TS;
    const int g    = blockIdx.y * 2 + gi;
    const int b    = blockIdx.z;

    // ---- stage both groups' 22x22 f32 halos cooperatively ----
    #pragma unroll
    for (int it = 0; it < 4; ++it) {
        int idx = t + it * 256;
        if (idx < 2 * HT * HT) {
            int g2  = idx / (HT * HT);
            int pos = idx - g2 * (HT * HT);
            int hh = pos / HT, ww = pos - hh * HT;
            int gh = h0 + hh - PAD, gw = w0 + ww - PAD;
            float4 v = make_float4(0.f, 0.f, 0.f, 0.f);
            if ((unsigned)gh < NH && (unsigned)gw < NW) {
                const float* pp = x + (size_t)(b*NC + (blockIdx.y*2 + g2)*CG)*HW
                                    + gh*NW + gw;
                v.x = pp[0]; v.y = pp[HW]; v.z = pp[2*HW]; v.w = pp[3*HW];
            }
            xs[g2][hh][ww] = v;
        }
    }
    __syncthreads();

    // ---- A-fragments ----
    const float* wg = w_span + (size_t)g*(KK*NR);
    bf16x8 A1[4];
    #pragma unroll
    for (int tt = 0; tt < 4; ++tt) {
        int tap = tt*16 + p; if (tap > 48) tap = 48;
        const float4* wr = (const float4*)(wg + tap*NR + (q & 1)*8);
        float4 u0 = wr[0], u1 = wr[1];
        float w8[8] = {u0.x,u0.y,u0.z,u0.w,u1.x,u1.y,u1.z,u1.w};
        bf16x8 a;
        #pragma unroll
        for (int i = 0; i < 8; ++i) {
            unsigned short h = bf16rn(w8[i]);
            unsigned short l = bf16rn(w8[i] - bf16tof(h));
            a[i] = (short)(q < 2 ? h : l);
        }
        A1[tt] = a;
    }

    // ---- bias ----
    const float* bg = b_span + g*KK;
    f32x4 bias[4];
    #pragma unroll
    for (int tt = 0; tt < 3; ++tt) {
        float4 bb = *(const float4*)(bg + tt*16 + q*4);
        bias[tt][0] = bb.x*L2E; bias[tt][1] = bb.y*L2E;
        bias[tt][2] = bb.z*L2E; bias[tt][3] = bb.w*L2E;
    }
    bias[3][0] = (q == 0) ? bg[48]*L2E : PADB;
    bias[3][1] = PADB; bias[3][2] = PADB; bias[3][3] = PADB;

    // ---- gather pointers (f32) ----
    const float4* gp[13];
    #pragma unroll
    for (int tt = 0; tt < 3; ++tt) {
        #pragma unroll
        for (int r = 0; r < 4; ++r) {
            int tap = tt*16 + q*4 + r;
            int i = tap / 7, j = tap - i*7;
            gp[tt*4+r] = &xs[gi][i + half*8][p + j];
        }
    }
    gp[12] = &xs[gi][6 + half*8][p + 6];

    const unsigned short* rb =
        redpk + (((size_t)b*HW + (size_t)(h0 + half*8)*NW + w0 + p) << 5)
              + ((q & 1) << 3);
    bf16x8 B1 = *(const bf16x8*)rb;            // r_hi slice
    bf16x8 B2 = *(const bf16x8*)(rb + 16);     // r_lo slice (ALL lanes live)

    const int hb = h0 + half*8;

    #pragma unroll
    for (int ph = 0; ph < 8; ++ph) {
        float4 vv[13];
        #pragma unroll
        for (int k = 0; k < 13; ++k)
            vv[k] = gp[k][ph*HT];              // ds_read_b128, imm offsets

        bf16x8 B1n = B1, B2n = B2;
        if (ph < 7) {                          // prefetch next row
            const unsigned short* rn = rb + (size_t)(ph+1)*(NW*32);
            B1n = *(const bf16x8*)rn;
            B2n = *(const bf16x8*)(rn + 16);
        }

        f32x4 ac[4];
        #pragma unroll
        for (int tt = 0; tt < 4; ++tt) {
            f32x4 c0 = __builtin_amdgcn_mfma_f32_16x16x32_bf16(A1[tt], B1, bias[tt], 0,0,0);
            ac[tt]   = __builtin_amdgcn_mfma_f32_16x16x32_bf16(A1[tt], B2, c0,      0,0,0);
        }

        float e[13];
        #pragma unroll
        for (int tt = 0; tt < 3; ++tt) {
            #pragma unroll
            for (int r = 0; r < 4; ++r)
                e[tt*4+r] = __builtin_amdgcn_exp2f(ac[tt][r]);
        }
        e[12] = __builtin_amdgcn_exp2f(ac[3][0]);

        float s0 = (e[0] + e[1]) + (e[2] + e[3]);
        float s1 = (e[4] + e[5]) + (e[6] + e[7]);
        float s2 = (e[8] + e[9]) + (e[10] + e[11]);
        float sum = (s0 + s1) + (s2 + e[12]);
        sum += __shfl_xor(sum, 16);
        sum += __shfl_xor(sum, 32);

        v2f a01 = {0.f, 0.f}, a23 = {0.f, 0.f};
        #pragma unroll
        for (int k = 0; k < 13; ++k) {
            float4 v = vv[k];
            v2f ee = {e[k], e[k]};
            a01 += ee * (v2f){v.x, v.y};       // v_pk_fma_f32
            a23 += ee * (v2f){v.z, v.w};
        }
        float g0 = a01[0], g1 = a01[1], g2 = a23[0], g3 = a23[1];
        g0 += __shfl_xor(g0, 16); g0 += __shfl_xor(g0, 32);
        g1 += __shfl_xor(g1, 16); g1 += __shfl_xor(g1, 32);
        g2 += __shfl_xor(g2, 16); g2 += __shfl_xor(g2, 32);
        g3 += __shfl_xor(g3, 16); g3 += __shfl_xor(g3, 32);

        if (q == 0) {
            float inv = 1.0f / sum;
            const int h = hb + ph, w = w0 + p;
            size_t ob = ((size_t)(b*NC + g*CG)*NH + h)*NW + w;
            out[ob]        = g0 * inv;
            out[ob + HW]   = g1 * inv;
            out[ob + 2*HW] = g2 * inv;
            out[ob + 3*HW] = g3 * inv;
        }
        B1 = B1n; B2 = B2n;
    }
}

extern "C" void kernel_launch(void* const* d_in, const int* in_sizes, int n_in,
                              void* d_out, int out_size, void* d_ws, size_t ws_size,
                              hipStream_t stream) {
    const float* x        = (const float*)d_in[0];
    const float* w_reduce = (const float*)d_in[1];
    const float* b_reduce = (const float*)d_in[2];
    const float* w_span   = (const float*)d_in[3];
    const float* b_span   = (const float*)d_in[4];
    float* out = (float*)d_out;
    unsigned short* redpk = (unsigned short*)d_ws;   // 4 MB

    red_kernel<<<dim3(NB*HW/256, 4), 256, 0, stream>>>(x, w_reduce, b_reduce, redpk);

    dim3 gridB(64, NG/2, NB);                        // 2048 blocks x 4 waves
    invol_kernel<<<gridB, 256, 0, stream>>>(x, w_span, b_span, redpk, out);
}

// Round 20
// 45.019 us; speedup vs baseline: 1.0761x; 1.0006x over previous
//
#include <hip/hip_runtime.h>
#include <hip/hip_fp16.h>

typedef float  f32x4  __attribute__((ext_vector_type(4)));
typedef float  v2f    __attribute__((ext_vector_type(2)));
typedef short  bf16x8 __attribute__((ext_vector_type(8)));

#define KS 7
#define NG 16
#define PAD 3
#define NB 4
#define NC 64
#define NH 128
#define NW 128
#define HW (NH*NW)
#define NR 16
#define CG 4
#define KK 49
#define L2E 1.44269504088896f
#define PADB -100000.0f
#define TS 16
#define HT 22

__device__ __forceinline__ unsigned short bf16rn(float f) {
    unsigned u = __float_as_uint(f);
    u += 0x7FFFu + ((u >> 16) & 1u);
    return (unsigned short)(u >> 16);
}
__device__ __forceinline__ float bf16tof(unsigned short h) {
    return __uint_as_float(((unsigned)h) << 16);
}

// ---- Kernel A: exact R15/R18 4-way version (proven) -------------------------
__global__ __launch_bounds__(256)
void red_kernel(const float* __restrict__ x,
                const float* __restrict__ w_reduce,
                const float* __restrict__ b_reduce,
                unsigned short* __restrict__ redpk) {
    __shared__ float wT[NC][4];
    const int t  = threadIdx.x;
    const int rq = blockIdx.y;                 // 0..3: which 4 r's
    { int e = t >> 6, c = t & 63; wT[c][e] = w_reduce[(rq*4+e)*NC + c]; }
    __syncthreads();

    const int pth = blockIdx.x*256 + t;        // 0..65535 = b*16384+pix
    const int b   = pth >> 14;
    const int pix = pth & 16383;

    float aa[4];
    #pragma unroll
    for (int i = 0; i < 4; ++i) aa[i] = b_reduce[rq*4+i];

    const float* xp = x + (size_t)b*(NC*HW) + pix;
    #pragma unroll 16
    for (int c = 0; c < NC; ++c) {
        float xv = xp[(size_t)c*HW];
        float4 ww = *(const float4*)&wT[c][0];
        aa[0] = fmaf(ww.x, xv, aa[0]);
        aa[1] = fmaf(ww.y, xv, aa[1]);
        aa[2] = fmaf(ww.z, xv, aa[2]);
        aa[3] = fmaf(ww.w, xv, aa[3]);
    }

    unsigned short hv[4], lv[4];
    #pragma unroll
    for (int i = 0; i < 4; ++i) {
        float sv = fmaxf(aa[i], 0.f) * L2E;
        unsigned short h = bf16rn(sv);
        hv[i] = h;
        lv[i] = bf16rn(sv - bf16tof(h));
    }
    unsigned short* rp = redpk + ((size_t)pth << 5);
    *(ushort4*)(rp + rq*4)      = make_ushort4(hv[0],hv[1],hv[2],hv[3]);
    *(ushort4*)(rp + 16 + rq*4) = make_ushort4(lv[0],lv[1],lv[2],lv[3]);
}

// ---- Kernel B: R18 minus the B2 zero-mask. --------------------------------
// Keeping r_lo live for q>=2 lanes adds the w_lo*r_lo cross-term, making the
// product (w_hi+w_lo)*(r_hi+r_lo) — exact w.r.t. the bf16 splits (MORE
// accurate than masking) — and removes the per-row cndmask/zz path.
__global__ __launch_bounds__(256, 4)
void invol_kernel(const float* __restrict__ x,
                  const float* __restrict__ w_span,
                  const float* __restrict__ b_span,
                  const unsigned short* __restrict__ redpk,
                  float* __restrict__ out) {
    __shared__ float4 xs[2][HT][HT];           // 15488 B

    const int t    = threadIdx.x;
    const int lane = t & 63;
    const int wv   = __builtin_amdgcn_readfirstlane(t >> 6);
    const int gi   = wv >> 1;
    const int half = wv & 1;
    const int p    = lane & 15;
    const int q    = lane >> 4;
    const int h0   = (blockIdx.x >> 3) * TS;
    const int w0   = (blockIdx.x & 7) * TS;
    const int g    = blockIdx.y * 2 + gi;
    const int b    = blockIdx.z;

    // ---- stage both groups' 22x22 f32 halos cooperatively ----
    #pragma unroll
    for (int it = 0; it < 4; ++it) {
        int idx = t + it * 256;
        if (idx < 2 * HT * HT) {
            int g2  = idx / (HT * HT);
            int pos = idx - g2 * (HT * HT);
            int hh = pos / HT, ww = pos - hh * HT;
            int gh = h0 + hh - PAD, gw = w0 + ww - PAD;
            float4 v = make_float4(0.f, 0.f, 0.f, 0.f);
            if ((unsigned)gh < NH && (unsigned)gw < NW) {
                const float* pp = x + (size_t)(b*NC + (blockIdx.y*2 + g2)*CG)*HW
                                    + gh*NW + gw;
                v.x = pp[0]; v.y = pp[HW]; v.z = pp[2*HW]; v.w = pp[3*HW];
            }
            xs[g2][hh][ww] = v;
        }
    }
    __syncthreads();

    // ---- A-fragments ----
    const float* wg = w_span + (size_t)g*(KK*NR);
    bf16x8 A1[4];
    #pragma unroll
    for (int tt = 0; tt < 4; ++tt) {
        int tap = tt*16 + p; if (tap > 48) tap = 48;
        const float4* wr = (const float4*)(wg + tap*NR + (q & 1)*8);
        float4 u0 = wr[0], u1 = wr[1];
        float w8[8] = {u0.x,u0.y,u0.z,u0.w,u1.x,u1.y,u1.z,u1.w};
        bf16x8 a;
        #pragma unroll
        for (int i = 0; i < 8; ++i) {
            unsigned short h = bf16rn(w8[i]);
            unsigned short l = bf16rn(w8[i] - bf16tof(h));
            a[i] = (short)(q < 2 ? h : l);
        }
        A1[tt] = a;
    }

    // ---- bias ----
    const float* bg = b_span + g*KK;
    f32x4 bias[4];
    #pragma unroll
    for (int tt = 0; tt < 3; ++tt) {
        float4 bb = *(const float4*)(bg + tt*16 + q*4);
        bias[tt][0] = bb.x*L2E; bias[tt][1] = bb.y*L2E;
        bias[tt][2] = bb.z*L2E; bias[tt][3] = bb.w*L2E;
    }
    bias[3][0] = (q == 0) ? bg[48]*L2E : PADB;
    bias[3][1] = PADB; bias[3][2] = PADB; bias[3][3] = PADB;

    // ---- gather pointers (f32) ----
    const float4* gp[13];
    #pragma unroll
    for (int tt = 0; tt < 3; ++tt) {
        #pragma unroll
        for (int r = 0; r < 4; ++r) {
            int tap = tt*16 + q*4 + r;
            int i = tap / 7, j = tap - i*7;
            gp[tt*4+r] = &xs[gi][i + half*8][p + j];
        }
    }
    gp[12] = &xs[gi][6 + half*8][p + 6];

    const unsigned short* rb =
        redpk + (((size_t)b*HW + (size_t)(h0 + half*8)*NW + w0 + p) << 5)
              + ((q & 1) << 3);
    bf16x8 B1 = *(const bf16x8*)rb;            // r_hi slice
    bf16x8 B2 = *(const bf16x8*)(rb + 16);     // r_lo slice (ALL lanes live)

    const int hb = h0 + half*8;

    #pragma unroll
    for (int ph = 0; ph < 8; ++ph) {
        float4 vv[13];
        #pragma unroll
        for (int k = 0; k < 13; ++k)
            vv[k] = gp[k][ph*HT];              // ds_read_b128, imm offsets

        bf16x8 B1n = B1, B2n = B2;
        if (ph < 7) {                          // prefetch next row
            const unsigned short* rn = rb + (size_t)(ph+1)*(NW*32);
            B1n = *(const bf16x8*)rn;
            B2n = *(const bf16x8*)(rn + 16);
        }

        f32x4 ac[4];
        #pragma unroll
        for (int tt = 0; tt < 4; ++tt) {
            f32x4 c0 = __builtin_amdgcn_mfma_f32_16x16x32_bf16(A1[tt], B1, bias[tt], 0,0,0);
            ac[tt]   = __builtin_amdgcn_mfma_f32_16x16x32_bf16(A1[tt], B2, c0,      0,0,0);
        }

        float e[13];
        #pragma unroll
        for (int tt = 0; tt < 3; ++tt) {
            #pragma unroll
            for (int r = 0; r < 4; ++r)
                e[tt*4+r] = __builtin_amdgcn_exp2f(ac[tt][r]);
        }
        e[12] = __builtin_amdgcn_exp2f(ac[3][0]);

        float s0 = (e[0] + e[1]) + (e[2] + e[3]);
        float s1 = (e[4] + e[5]) + (e[6] + e[7]);
        float s2 = (e[8] + e[9]) + (e[10] + e[11]);
        float sum = (s0 + s1) + (s2 + e[12]);
        sum += __shfl_xor(sum, 16);
        sum += __shfl_xor(sum, 32);

        v2f a01 = {0.f, 0.f}, a23 = {0.f, 0.f};
        #pragma unroll
        for (int k = 0; k < 13; ++k) {
            float4 v = vv[k];
            v2f ee = {e[k], e[k]};
            a01 += ee * (v2f){v.x, v.y};       // v_pk_fma_f32
            a23 += ee * (v2f){v.z, v.w};
        }
        float g0 = a01[0], g1 = a01[1], g2 = a23[0], g3 = a23[1];
        g0 += __shfl_xor(g0, 16); g0 += __shfl_xor(g0, 32);
        g1 += __shfl_xor(g1, 16); g1 += __shfl_xor(g1, 32);
        g2 += __shfl_xor(g2, 16); g2 += __shfl_xor(g2, 32);
        g3 += __shfl_xor(g3, 16); g3 += __shfl_xor(g3, 32);

        if (q == 0) {
            float inv = 1.0f / sum;
            const int h = hb + ph, w = w0 + p;
            size_t ob = ((size_t)(b*NC + g*CG)*NH + h)*NW + w;
            out[ob]        = g0 * inv;
            out[ob + HW]   = g1 * inv;
            out[ob + 2*HW] = g2 * inv;
            out[ob + 3*HW] = g3 * inv;
        }
        B1 = B1n; B2 = B2n;
    }
}

extern "C" void kernel_launch(void* const* d_in, const int* in_sizes, int n_in,
                              void* d_out, int out_size, void* d_ws, size_t ws_size,
                              hipStream_t stream) {
    const float* x        = (const float*)d_in[0];
    const float* w_reduce = (const float*)d_in[1];
    const float* b_reduce = (const float*)d_in[2];
    const float* w_span   = (const float*)d_in[3];
    const float* b_span   = (const float*)d_in[4];
    float* out = (float*)d_out;
    unsigned short* redpk = (unsigned short*)d_ws;   // 4 MB

    red_kernel<<<dim3(NB*HW/256, 4), 256, 0, stream>>>(x, w_reduce, b_reduce, redpk);

    dim3 gridB(64, NG/2, NB);                        // 2048 blocks x 4 waves
    invol_kernel<<<gridB, 256, 0, stream>>>(x, w_span, b_span, redpk, out);
}

// Round 21
// 44.866 us; speedup vs baseline: 1.0798x; 1.0034x over previous
//
#include <hip/hip_runtime.h>
#include <hip/hip_fp16.h>

typedef float  f32x4  __attribute__((ext_vector_type(4)));
typedef float  v2f    __attribute__((ext_vector_type(2)));
typedef short  bf16x8 __attribute__((ext_vector_type(8)));
typedef int    v2i    __attribute__((ext_vector_type(2)));

#define KS 7
#define NG 16
#define PAD 3
#define NB 4
#define NC 64
#define NH 128
#define NW 128
#define HW (NH*NW)
#define NR 16
#define CG 4
#define KK 49
#define L2E 1.44269504088896f
#define PADB -100000.0f
#define TS 16
#define HT 22

__device__ __forceinline__ unsigned short bf16rn(float f) {
    unsigned u = __float_as_uint(f);
    u += 0x7FFFu + ((u >> 16) & 1u);
    return (unsigned short)(u >> 16);
}
__device__ __forceinline__ float bf16tof(unsigned short h) {
    return __uint_as_float(((unsigned)h) << 16);
}
// xor-32 halves-sum on the VALU via the documented builtin (NOT raw asm —
// R16's asm form let the compiler alias the two operands). With both inputs
// = v: ret.x = v_lo in both halves, ret.y = v_hi in both halves, so
// ret.x+ret.y == v + shfl_xor(v,32) bit-identically (commutativity only).
__device__ __forceinline__ float xor32_sum(float v) {
    v2i r = __builtin_amdgcn_permlane32_swap(__float_as_int(v), __float_as_int(v),
                                             false, false);
    return __int_as_float(r.x) + __int_as_float(r.y);
}

// ---- Kernel A: exact R15/R18 4-way version (proven) -------------------------
__global__ __launch_bounds__(256)
void red_kernel(const float* __restrict__ x,
                const float* __restrict__ w_reduce,
                const float* __restrict__ b_reduce,
                unsigned short* __restrict__ redpk) {
    __shared__ float wT[NC][4];
    const int t  = threadIdx.x;
    const int rq = blockIdx.y;                 // 0..3: which 4 r's
    { int e = t >> 6, c = t & 63; wT[c][e] = w_reduce[(rq*4+e)*NC + c]; }
    __syncthreads();

    const int pth = blockIdx.x*256 + t;        // 0..65535 = b*16384+pix
    const int b   = pth >> 14;
    const int pix = pth & 16383;

    float aa[4];
    #pragma unroll
    for (int i = 0; i < 4; ++i) aa[i] = b_reduce[rq*4+i];

    const float* xp = x + (size_t)b*(NC*HW) + pix;
    #pragma unroll 16
    for (int c = 0; c < NC; ++c) {
        float xv = xp[(size_t)c*HW];
        float4 ww = *(const float4*)&wT[c][0];
        aa[0] = fmaf(ww.x, xv, aa[0]);
        aa[1] = fmaf(ww.y, xv, aa[1]);
        aa[2] = fmaf(ww.z, xv, aa[2]);
        aa[3] = fmaf(ww.w, xv, aa[3]);
    }

    unsigned short hv[4], lv[4];
    #pragma unroll
    for (int i = 0; i < 4; ++i) {
        float sv = fmaxf(aa[i], 0.f) * L2E;
        unsigned short h = bf16rn(sv);
        hv[i] = h;
        lv[i] = bf16rn(sv - bf16tof(h));
    }
    unsigned short* rp = redpk + ((size_t)pth << 5);
    *(ushort4*)(rp + rq*4)      = make_ushort4(hv[0],hv[1],hv[2],hv[3]);
    *(ushort4*)(rp + 16 + rq*4) = make_ushort4(lv[0],lv[1],lv[2],lv[3]);
}

// ---- Kernel B: R20 with the 5 xor-32 shuffles moved to VALU permlane --------
__global__ __launch_bounds__(256, 4)
void invol_kernel(const float* __restrict__ x,
                  const float* __restrict__ w_span,
                  const float* __restrict__ b_span,
                  const unsigned short* __restrict__ redpk,
                  float* __restrict__ out) {
    __shared__ float4 xs[2][HT][HT];           // 15488 B

    const int t    = threadIdx.x;
    const int lane = t & 63;
    const int wv   = __builtin_amdgcn_readfirstlane(t >> 6);
    const int gi   = wv >> 1;
    const int half = wv & 1;
    const int p    = lane & 15;
    const int q    = lane >> 4;
    const int h0   = (blockIdx.x >> 3) * TS;
    const int w0   = (blockIdx.x & 7) * TS;
    const int g    = blockIdx.y * 2 + gi;
    const int b    = blockIdx.z;

    // ---- stage both groups' 22x22 f32 halos cooperatively ----
    #pragma unroll
    for (int it = 0; it < 4; ++it) {
        int idx = t + it * 256;
        if (idx < 2 * HT * HT) {
            int g2  = idx / (HT * HT);
            int pos = idx - g2 * (HT * HT);
            int hh = pos / HT, ww = pos - hh * HT;
            int gh = h0 + hh - PAD, gw = w0 + ww - PAD;
            float4 v = make_float4(0.f, 0.f, 0.f, 0.f);
            if ((unsigned)gh < NH && (unsigned)gw < NW) {
                const float* pp = x + (size_t)(b*NC + (blockIdx.y*2 + g2)*CG)*HW
                                    + gh*NW + gw;
                v.x = pp[0]; v.y = pp[HW]; v.z = pp[2*HW]; v.w = pp[3*HW];
            }
            xs[g2][hh][ww] = v;
        }
    }
    __syncthreads();

    // ---- A-fragments ----
    const float* wg = w_span + (size_t)g*(KK*NR);
    bf16x8 A1[4];
    #pragma unroll
    for (int tt = 0; tt < 4; ++tt) {
        int tap = tt*16 + p; if (tap > 48) tap = 48;
        const float4* wr = (const float4*)(wg + tap*NR + (q & 1)*8);
        float4 u0 = wr[0], u1 = wr[1];
        float w8[8] = {u0.x,u0.y,u0.z,u0.w,u1.x,u1.y,u1.z,u1.w};
        bf16x8 a;
        #pragma unroll
        for (int i = 0; i < 8; ++i) {
            unsigned short h = bf16rn(w8[i]);
            unsigned short l = bf16rn(w8[i] - bf16tof(h));
            a[i] = (short)(q < 2 ? h : l);
        }
        A1[tt] = a;
    }

    // ---- bias ----
    const float* bg = b_span + g*KK;
    f32x4 bias[4];
    #pragma unroll
    for (int tt = 0; tt < 3; ++tt) {
        float4 bb = *(const float4*)(bg + tt*16 + q*4);
        bias[tt][0] = bb.x*L2E; bias[tt][1] = bb.y*L2E;
        bias[tt][2] = bb.z*L2E; bias[tt][3] = bb.w*L2E;
    }
    bias[3][0] = (q == 0) ? bg[48]*L2E : PADB;
    bias[3][1] = PADB; bias[3][2] = PADB; bias[3][3] = PADB;

    // ---- gather pointers (f32) ----
    const float4* gp[13];
    #pragma unroll
    for (int tt = 0; tt < 3; ++tt) {
        #pragma unroll
        for (int r = 0; r < 4; ++r) {
            int tap = tt*16 + q*4 + r;
            int i = tap / 7, j = tap - i*7;
            gp[tt*4+r] = &xs[gi][i + half*8][p + j];
        }
    }
    gp[12] = &xs[gi][6 + half*8][p + 6];

    const unsigned short* rb =
        redpk + (((size_t)b*HW + (size_t)(h0 + half*8)*NW + w0 + p) << 5)
              + ((q & 1) << 3);
    bf16x8 B1 = *(const bf16x8*)rb;            // r_hi slice
    bf16x8 B2 = *(const bf16x8*)(rb + 16);     // r_lo slice (all lanes live)

    const int hb = h0 + half*8;

    #pragma unroll
    for (int ph = 0; ph < 8; ++ph) {
        float4 vv[13];
        #pragma unroll
        for (int k = 0; k < 13; ++k)
            vv[k] = gp[k][ph*HT];              // ds_read_b128, imm offsets

        bf16x8 B1n = B1, B2n = B2;
        if (ph < 7) {                          // prefetch next row
            const unsigned short* rn = rb + (size_t)(ph+1)*(NW*32);
            B1n = *(const bf16x8*)rn;
            B2n = *(const bf16x8*)(rn + 16);
        }

        f32x4 ac[4];
        #pragma unroll
        for (int tt = 0; tt < 4; ++tt) {
            f32x4 c0 = __builtin_amdgcn_mfma_f32_16x16x32_bf16(A1[tt], B1, bias[tt], 0,0,0);
            ac[tt]   = __builtin_amdgcn_mfma_f32_16x16x32_bf16(A1[tt], B2, c0,      0,0,0);
        }

        float e[13];
        #pragma unroll
        for (int tt = 0; tt < 3; ++tt) {
            #pragma unroll
            for (int r = 0; r < 4; ++r)
                e[tt*4+r] = __builtin_amdgcn_exp2f(ac[tt][r]);
        }
        e[12] = __builtin_amdgcn_exp2f(ac[3][0]);

        float s0 = (e[0] + e[1]) + (e[2] + e[3]);
        float s1 = (e[4] + e[5]) + (e[6] + e[7]);
        float s2 = (e[8] + e[9]) + (e[10] + e[11]);
        float sum = (s0 + s1) + (s2 + e[12]);
        sum += __shfl_xor(sum, 16);
        sum = xor32_sum(sum);                  // VALU (was ds_bpermute)

        v2f a01 = {0.f, 0.f}, a23 = {0.f, 0.f};
        #pragma unroll
        for (int k = 0; k < 13; ++k) {
            float4 v = vv[k];
            v2f ee = {e[k], e[k]};
            a01 += ee * (v2f){v.x, v.y};       // v_pk_fma_f32
            a23 += ee * (v2f){v.z, v.w};
        }
        float g0 = a01[0], g1 = a01[1], g2 = a23[0], g3 = a23[1];
        g0 += __shfl_xor(g0, 16); g0 = xor32_sum(g0);
        g1 += __shfl_xor(g1, 16); g1 = xor32_sum(g1);
        g2 += __shfl_xor(g2, 16); g2 = xor32_sum(g2);
        g3 += __shfl_xor(g3, 16); g3 = xor32_sum(g3);

        if (q == 0) {
            float inv = 1.0f / sum;
            const int h = hb + ph, w = w0 + p;
            size_t ob = ((size_t)(b*NC + g*CG)*NH + h)*NW + w;
            out[ob]        = g0 * inv;
            out[ob + HW]   = g1 * inv;
            out[ob + 2*HW] = g2 * inv;
            out[ob + 3*HW] = g3 * inv;
        }
        B1 = B1n; B2 = B2n;
    }
}

extern "C" void kernel_launch(void* const* d_in, const int* in_sizes, int n_in,
                              void* d_out, int out_size, void* d_ws, size_t ws_size,
                              hipStream_t stream) {
    const float* x        = (const float*)d_in[0];
    const float* w_reduce = (const float*)d_in[1];
    const float* b_reduce = (const float*)d_in[2];
    const float* w_span   = (const float*)d_in[3];
    const float* b_span   = (const float*)d_in[4];
    float* out = (float*)d_out;
    unsigned short* redpk = (unsigned short*)d_ws;   // 4 MB

    red_kernel<<<dim3(NB*HW/256, 4), 256, 0, stream>>>(x, w_reduce, b_reduce, redpk);

    dim3 gridB(64, NG/2, NB);                        // 2048 blocks x 4 waves
    invol_kernel<<<gridB, 256, 0, stream>>>(x, w_span, b_span, redpk, out);
}